// Round 1
// baseline (251.964 us; speedup 1.0000x reference)
//
#include <hip/hip_runtime.h>
#include <math.h>

#define BATCH 131072
#define DIM 256
#define NK 5
#define BT 3.0f

__global__ __launch_bounds__(256, 4) void rqs_kernel(
    const float* __restrict__ u,
    const float* __restrict__ wp,
    const float* __restrict__ hp,
    const float* __restrict__ dp,
    float* __restrict__ x_out,
    float* __restrict__ ld_out)
{
    // tab layout: [k]*DIM + swizzled_dim
    //  [0..4]   cum_w[k]   (knot x positions, k=0..4)
    //  [5..9]   1/width[k]
    //  [10..14] cum_h[k]   (knot y positions)
    //  [15..19] height[k]
    //  [20..25] deriv[k]   (k=0..5; deriv[0]=deriv[5]=1)
    __shared__ float tab[26 * DIM];
    const int tid = threadIdx.x;

    // ---------- per-dim table precompute: thread t handles dim t ----------
    {
        const int dm = tid;
        const int sp = ((dm & 3) << 6) | (dm >> 2);   // swizzled position
        float v[NK];
        float mx, sum, scale, c;

        // widths = softmax(w)*6
        mx = -1e30f;
        #pragma unroll
        for (int k = 0; k < NK; k++) { v[k] = wp[dm * NK + k]; mx = fmaxf(mx, v[k]); }
        sum = 0.f;
        #pragma unroll
        for (int k = 0; k < NK; k++) { v[k] = expf(v[k] - mx); sum += v[k]; }
        scale = 6.0f / sum;
        c = -BT;
        #pragma unroll
        for (int k = 0; k < NK; k++) {
            float wid = v[k] * scale;
            tab[k * DIM + sp]       = c;            // cum_w[k]
            tab[(5 + k) * DIM + sp] = 1.0f / wid;   // 1/width
            c += wid;
        }

        // heights = softmax(h)*6
        mx = -1e30f;
        #pragma unroll
        for (int k = 0; k < NK; k++) { v[k] = hp[dm * NK + k]; mx = fmaxf(mx, v[k]); }
        sum = 0.f;
        #pragma unroll
        for (int k = 0; k < NK; k++) { v[k] = expf(v[k] - mx); sum += v[k]; }
        scale = 6.0f / sum;
        c = -BT;
        #pragma unroll
        for (int k = 0; k < NK; k++) {
            float hei = v[k] * scale;
            tab[(10 + k) * DIM + sp] = c;           // cum_h[k]
            tab[(15 + k) * DIM + sp] = hei;         // height
            c += hei;
        }

        // derivs = [1, softplus(d0..d3), 1]
        tab[20 * DIM + sp] = 1.0f;
        #pragma unroll
        for (int k = 0; k < 4; k++)
            tab[(21 + k) * DIM + sp] = log1pf(expf(dp[dm * 4 + k]));
        tab[25 * DIM + sp] = 1.0f;
    }
    __syncthreads();

    const int lane = tid & 63;
    const int wv   = tid >> 6;

    // preload interior knots cum_w[1..4] for this thread's 4 dims (4*lane + j)
    float kn[4][4];
    #pragma unroll
    for (int j = 0; j < 4; j++) {
        const int sp = (j << 6) | lane;
        #pragma unroll
        for (int i = 0; i < 4; i++)
            kn[j][i] = tab[(i + 1) * DIM + sp];
    }

    const int gw = (blockIdx.x << 2) | wv;   // global wave id; one wave = one row
    const int nw = gridDim.x << 2;

    for (int row = gw; row < BATCH; row += nw) {
        const float4 uv = reinterpret_cast<const float4*>(u + (size_t)row * DIM)[lane];
        float uin[4] = {uv.x, uv.y, uv.z, uv.w};
        float xo[4];
        float ldsum = 0.f;
        #pragma unroll
        for (int j = 0; j < 4; j++) {
            float uval = uin[j];
            float uc = fminf(fmaxf(uval, -BT), BT);
            bool inside = (uval >= -BT) && (uval <= BT);
            int idx = 0;
            idx += (uc >= kn[j][0]);
            idx += (uc >= kn[j][1]);
            idx += (uc >= kn[j][2]);
            idx += (uc >= kn[j][3]);
            const int a = idx * DIM + ((j << 6) | lane);
            float xk  = tab[a];
            float iw  = tab[a + 5 * DIM];
            float yk  = tab[a + 10 * DIM];
            float hk  = tab[a + 15 * DIM];
            float dk  = tab[a + 20 * DIM];
            float dk1 = tab[a + 21 * DIM];

            float delta = hk * iw;                       // bin slope
            float theta = (uc - xk) * iw;
            float omt   = 1.0f - theta;
            float t1m   = theta * omt;
            float th2   = theta * theta;
            float denom = delta + (dk + dk1 - 2.0f * delta) * t1m;
            float inv_d = __fdividef(1.0f, denom);
            float num   = hk * (delta * th2 + dk * t1m);
            float x_in  = yk + num * inv_d;
            float ldn   = (delta * delta) *
                          (dk1 * th2 + 2.0f * delta * t1m + dk * omt * omt);
            float ld    = __logf(ldn * inv_d * inv_d);   // log(ldn) - 2*log(denom)

            xo[j] = inside ? x_in : uval;
            ldsum += inside ? ld : 0.0f;
        }
        reinterpret_cast<float4*>(x_out + (size_t)row * DIM)[lane] =
            make_float4(xo[0], xo[1], xo[2], xo[3]);

        #pragma unroll
        for (int off = 32; off > 0; off >>= 1)
            ldsum += __shfl_down(ldsum, off, 64);
        if (lane == 0) ld_out[row] = ldsum;
    }
}

extern "C" void kernel_launch(void* const* d_in, const int* in_sizes, int n_in,
                              void* d_out, int out_size, void* d_ws, size_t ws_size,
                              hipStream_t stream) {
    const float* u  = (const float*)d_in[0];
    const float* w  = (const float*)d_in[1];
    const float* h  = (const float*)d_in[2];
    const float* dd = (const float*)d_in[3];
    float* x  = (float*)d_out;
    float* ld = x + (size_t)BATCH * DIM;
    rqs_kernel<<<2048, 256, 0, stream>>>(u, w, h, dd, x, ld);
}

// Round 2
// 246.542 us; speedup vs baseline: 1.0220x; 1.0220x over previous
//
#include <hip/hip_runtime.h>
#include <math.h>

#define BATCH 131072
#define DIM 256
#define NK 5
#define BT 3.0f

__global__ __launch_bounds__(256, 5) void rqs_kernel(
    const float* __restrict__ u,
    const float* __restrict__ wp,
    const float* __restrict__ hp,
    const float* __restrict__ dp,
    float* __restrict__ x_out,
    float* __restrict__ ld_out)
{
    // tabA[k*DIM + dim] = (xk, 1/width, yk, height) for bin k
    // tabB[k*DIM + dim] = (deriv[k], deriv[k+1])
    __shared__ float4 tabA[NK * DIM];
    __shared__ float2 tabB[NK * DIM];
    const int tid = threadIdx.x;

    // ---------- per-dim table precompute: thread t handles dim t ----------
    {
        const int dm = tid;
        float v[NK];
        float mx, sum, scale, c;
        float wid[NK], xpos[NK], hei[NK], ypos[NK], dv[NK + 1];

        // widths = softmax(w)*6, cumulative x-positions
        mx = -1e30f;
        #pragma unroll
        for (int k = 0; k < NK; k++) { v[k] = wp[dm * NK + k]; mx = fmaxf(mx, v[k]); }
        sum = 0.f;
        #pragma unroll
        for (int k = 0; k < NK; k++) { v[k] = expf(v[k] - mx); sum += v[k]; }
        scale = 6.0f / sum;
        c = -BT;
        #pragma unroll
        for (int k = 0; k < NK; k++) { wid[k] = v[k] * scale; xpos[k] = c; c += wid[k]; }

        // heights = softmax(h)*6, cumulative y-positions
        mx = -1e30f;
        #pragma unroll
        for (int k = 0; k < NK; k++) { v[k] = hp[dm * NK + k]; mx = fmaxf(mx, v[k]); }
        sum = 0.f;
        #pragma unroll
        for (int k = 0; k < NK; k++) { v[k] = expf(v[k] - mx); sum += v[k]; }
        scale = 6.0f / sum;
        c = -BT;
        #pragma unroll
        for (int k = 0; k < NK; k++) { hei[k] = v[k] * scale; ypos[k] = c; c += hei[k]; }

        // derivs = [1, softplus(d0..d3), 1]
        dv[0] = 1.0f; dv[NK] = 1.0f;
        #pragma unroll
        for (int k = 0; k < 4; k++) dv[1 + k] = log1pf(expf(dp[dm * 4 + k]));

        #pragma unroll
        for (int k = 0; k < NK; k++) {
            tabA[k * DIM + dm] = make_float4(xpos[k], 1.0f / wid[k], ypos[k], hei[k]);
            tabB[k * DIM + dm] = make_float2(dv[k], dv[k + 1]);
        }
    }
    __syncthreads();

    const int lane = tid & 63;
    const int wv   = tid >> 6;

    // this thread owns dims lane, lane+64, lane+128, lane+192
    // preload interior knots cum_w[1..4] for binning
    float kn[4][4];
    #pragma unroll
    for (int j = 0; j < 4; j++) {
        #pragma unroll
        for (int i = 0; i < 4; i++)
            kn[j][i] = tabA[(i + 1) * DIM + lane + 64 * j].x;
    }

    const int gw = (blockIdx.x << 2) | wv;   // global wave id
    const int nw = gridDim.x << 2;

    for (int base = gw * 2; base < BATCH; base += nw * 2) {
        // ---- load u for 2 rows x 4 dims (8 coalesced b32 loads, all in flight) ----
        float uin[2][4];
        #pragma unroll
        for (int rr = 0; rr < 2; rr++) {
            const float* up = u + (size_t)(base + rr) * DIM + lane;
            #pragma unroll
            for (int j = 0; j < 4; j++) uin[rr][j] = up[64 * j];
        }

        float ldsum[2] = {0.f, 0.f};
        #pragma unroll
        for (int rr = 0; rr < 2; rr++) {
            float xo[4];
            #pragma unroll
            for (int j = 0; j < 4; j++) {
                float uval = uin[rr][j];
                float uc = fminf(fmaxf(uval, -BT), BT);
                bool inside = (uval >= -BT) && (uval <= BT);
                int idx = 0;
                idx += (uc >= kn[j][0]);
                idx += (uc >= kn[j][1]);
                idx += (uc >= kn[j][2]);
                idx += (uc >= kn[j][3]);
                const int a = idx * DIM + lane + 64 * j;
                float4 A  = tabA[a];
                float2 Bv = tabB[a];
                float xk = A.x, iw = A.y, yk = A.z, hk = A.w;
                float dk = Bv.x, dk1 = Bv.y;

                float delta = hk * iw;
                float theta = (uc - xk) * iw;
                float omt   = 1.0f - theta;
                float t1m   = theta * omt;
                float th2   = theta * theta;
                float denom = delta + (dk + dk1 - 2.0f * delta) * t1m;
                float inv_d = __fdividef(1.0f, denom);
                float num   = hk * (delta * th2 + dk * t1m);
                float x_in  = yk + num * inv_d;
                float ldn   = (delta * delta) *
                              (dk1 * th2 + 2.0f * delta * t1m + dk * omt * omt);
                float ld    = __logf(ldn * inv_d * inv_d);

                xo[j] = inside ? x_in : uval;
                ldsum[rr] += inside ? ld : 0.0f;
            }
            float* xp = x_out + (size_t)(base + rr) * DIM + lane;
            #pragma unroll
            for (int j = 0; j < 4; j++)
                __builtin_nontemporal_store(xo[j], xp + 64 * j);
        }

        // two independent 64-lane reduction chains
        #pragma unroll
        for (int off = 32; off > 0; off >>= 1) {
            ldsum[0] += __shfl_down(ldsum[0], off, 64);
            ldsum[1] += __shfl_down(ldsum[1], off, 64);
        }
        if (lane == 0) {
            __builtin_nontemporal_store(ldsum[0], ld_out + base);
            __builtin_nontemporal_store(ldsum[1], ld_out + base + 1);
        }
    }
}

extern "C" void kernel_launch(void* const* d_in, const int* in_sizes, int n_in,
                              void* d_out, int out_size, void* d_ws, size_t ws_size,
                              hipStream_t stream) {
    const float* u  = (const float*)d_in[0];
    const float* w  = (const float*)d_in[1];
    const float* h  = (const float*)d_in[2];
    const float* dd = (const float*)d_in[3];
    float* x  = (float*)d_out;
    float* ld = x + (size_t)BATCH * DIM;
    rqs_kernel<<<2048, 256, 0, stream>>>(u, w, h, dd, x, ld);
}